// Round 6
// baseline (2846.227 us; speedup 1.0000x reference)
//
#include <hip/hip_runtime.h>
#include <hip/hip_bf16.h>
#include <cstdio>

// GCNTox21 — round 6. ROOT CAUSE FIXED: inputs are FLOAT32 (per reference
// jnp.float32; the "(bf16)" in the test label is only the tolerance mode).
// Round-5 probe V=4 proved hbuf non-finite -> u16 reinterpretation of fp32.
// Pipeline: per-node projections Pd/Ps + per-edge 16-dim mini-dot + relu +
// atomic fp32 aggregation at dst + post-agg node GEMM + BN + mean-pool + fc.

#define N_NODES 100000
#define N_EDGES 1600000
#define NUM_GRAPHS 4096

typedef unsigned short u16;
typedef unsigned int u32;

__device__ __forceinline__ float b2f(u16 u) { union { u32 i; float f; } c; c.i = ((u32)u) << 16; return c.f; }
__device__ __forceinline__ u16 f2b(float f) {
    __hip_bfloat16 h = __float2bfloat16(f);
    return *reinterpret_cast<u16*>(&h);
}

template <typename ST> __device__ __forceinline__ void st_store(ST* p, float v);
template <> __device__ __forceinline__ void st_store<float>(float* p, float v) { *p = v; }
template <> __device__ __forceinline__ void st_store<u16>(u16* p, float v) { *p = f2b(v); }
template <typename ST> __device__ __forceinline__ float st_load(const ST* p);
template <> __device__ __forceinline__ float st_load<float>(const float* p) { return *p; }
template <> __device__ __forceinline__ float st_load<u16>(const u16* p) { return b2f(*p); }

__global__ __launch_bounds__(256) void hist_k(const int* __restrict__ dst, int* __restrict__ hist) {
    int e = blockIdx.x * 256 + threadIdx.x;
    if (e < N_EDGES) atomicAdd(&hist[dst[e]], 1);
}

// e16[e][k] = relu(edge_attr[e] @ We + be), staged bf16 [E,16]
__global__ __launch_bounds__(256) void edge_emb_k(const float* __restrict__ ea,
        const float* __restrict__ We, const float* __restrict__ be, u16* __restrict__ e16) {
    int idx = blockIdx.x * 256 + threadIdx.x;
    if (idx >= N_EDGES * 16) return;
    int e = idx >> 4, k = idx & 15;
    float acc = be[k];
#pragma unroll
    for (int j = 0; j < 8; ++j) acc += ea[(size_t)e * 8 + j] * We[j * 16 + k];
    e16[idx] = f2b(fmaxf(acc, 0.f));
}

// h0 = relu(x @ Wn + bn), fp32 [N,64]
__global__ __launch_bounds__(256) void node_emb_k(const float* __restrict__ x,
        const float* __restrict__ Wn, const float* __restrict__ bn_, float* __restrict__ h) {
    int idx = blockIdx.x * 256 + threadIdx.x;
    if (idx >= N_NODES * 64) return;
    int v = idx >> 6, c = idx & 63;
    float acc = bn_[c];
    for (int k = 0; k < 32; ++k) acc += x[(size_t)v * 32 + k] * Wn[(size_t)k * 64 + c];
    h[idx] = fmaxf(acc, 0.f);
}

// Pd = h @ Wa[0:F] + ba ; Ps = h @ Wa[F:2F]
template <int F, int H, typename ST>
__global__ __launch_bounds__(256) void proj_k(const float* __restrict__ h,
        const float* __restrict__ Wa, const float* __restrict__ ba,
        ST* __restrict__ Pd, ST* __restrict__ Ps) {
    int idx = blockIdx.x * 256 + threadIdx.x;
    if (idx >= N_NODES * H) return;
    int v = idx / H, c = idx % H;
    float ad = ba[c], as = 0.f;
    const float* hr = h + (size_t)v * F;
    for (int k = 0; k < F; ++k) {
        float hk = hr[k];
        ad += hk * Wa[(size_t)k * H + c];
        as += hk * Wa[(size_t)(F + k) * H + c];
    }
    st_store(&Pd[idx], ad);
    st_store(&Ps[idx], as);
}

// z = Pd[dst][c] + Ps[src][c] + e16[e]·Wa_edge[:,c]; relu; atomicAdd A[dst][c]
template <int H, typename ST>
__global__ __launch_bounds__(256) void eagg_k(const int* __restrict__ src, const int* __restrict__ dst,
        const u16* __restrict__ e16, const ST* __restrict__ Pd, const ST* __restrict__ Ps,
        const float* __restrict__ Wa, int rowoff, float* __restrict__ A) {
    long long idx = (long long)blockIdx.x * 256 + threadIdx.x;
    if (idx >= (long long)N_EDGES * H) return;
    int e = (int)(idx / H), c = (int)(idx % H);
    int d = dst[e], s = src[e];
    float z = st_load(&Pd[(size_t)d * H + c]) + st_load(&Ps[(size_t)s * H + c]);
#pragma unroll
    for (int k = 0; k < 16; ++k)
        z += b2f(e16[(size_t)e * 16 + k]) * Wa[(size_t)(rowoff + k) * H + c];
    atomicAdd(&A[(size_t)d * H + c], fmaxf(z, 0.f));
}

// y[v][co] = (A[v]/deg) @ Wb + bb  (deg>0), else 0
template <int H, int Fo>
__global__ __launch_bounds__(256) void ymlp_k(const float* __restrict__ A, const int* __restrict__ deg,
        const float* __restrict__ Wb, const float* __restrict__ bb, float* __restrict__ y) {
    int idx = blockIdx.x * 256 + threadIdx.x;
    if (idx >= N_NODES * Fo) return;
    int v = idx / Fo, co = idx % Fo;
    float acc = 0.f;
    const float* Ar = A + (size_t)v * H;
    for (int k = 0; k < H; ++k) acc += Ar[k] * Wb[(size_t)k * Fo + co];
    int d = deg[v];
    y[idx] = (d > 0) ? (acc / (float)d + bb[co]) : 0.f;
}

template <int Fo>
__global__ __launch_bounds__(256) void stats_k(const float* __restrict__ y, float* __restrict__ stats) {
    int co = blockIdx.x;
    __shared__ float sm[256];
    float s1 = 0.f, s2 = 0.f;
    for (int v = threadIdx.x; v < N_NODES; v += 256) {
        float yv = y[(size_t)v * Fo + co];
        s1 += yv; s2 += yv * yv;
    }
    sm[threadIdx.x] = s1;
    __syncthreads();
    for (int o = 128; o > 0; o >>= 1) {
        if (threadIdx.x < o) sm[threadIdx.x] += sm[threadIdx.x + o];
        __syncthreads();
    }
    if (threadIdx.x == 0) stats[co] = sm[0];
    __syncthreads();
    sm[threadIdx.x] = s2;
    __syncthreads();
    for (int o = 128; o > 0; o >>= 1) {
        if (threadIdx.x < o) sm[threadIdx.x] += sm[threadIdx.x + o];
        __syncthreads();
    }
    if (threadIdx.x == 0) stats[Fo + co] = sm[0];
}

template <int Fo>
__global__ __launch_bounds__(256) void bnrelu_k(float* __restrict__ y,
        const float* __restrict__ stats, const float* __restrict__ g, const float* __restrict__ beta) {
    int idx = blockIdx.x * 256 + threadIdx.x;
    if (idx >= N_NODES * Fo) return;
    int co = idx % Fo;
    const float invN = 1.0f / (float)N_NODES;
    float mu = stats[co] * invN;
    float ex2 = stats[Fo + co] * invN;
    float var = fmaxf(ex2 - mu * mu, 0.f);
    float rs = rsqrtf(var + 1e-5f);
    y[idx] = fmaxf((y[idx] - mu) * rs * g[co] + beta[co], 0.f);
}

__global__ __launch_bounds__(256) void pool_k(const float* __restrict__ h,
        const int* __restrict__ batch, float* __restrict__ pool, int* __restrict__ gcnt) {
    int idx = blockIdx.x * 256 + threadIdx.x;
    if (idx >= N_NODES * 16) return;
    int v = idx >> 4, c = idx & 15;
    int b = batch[v];
    atomicAdd(&pool[b * 16 + c], h[idx]);
    if (c == 0) atomicAdd(&gcnt[b], 1);
}

__global__ __launch_bounds__(256) void out_k(const float* __restrict__ pool,
        const int* __restrict__ gcnt, const float* __restrict__ Wfc,
        const float* __restrict__ bfc, float* __restrict__ out) {
    int idx = blockIdx.x * 256 + threadIdx.x;
    if (idx >= NUM_GRAPHS * 12) return;
    int g = idx / 12, o = idx % 12;
    int cnt = gcnt[g];
    float inv = 1.0f / (float)(cnt > 0 ? cnt : 1);
    float acc = bfc[o];
#pragma unroll
    for (int k = 0; k < 16; ++k) acc += pool[g * 16 + k] * inv * Wfc[k * 12 + o];
    out[idx] = 1.0f / (1.0f + expf(-acc));
}

template <typename ST>
static void run_pipeline(void* const* d_in, void* d_out, char* base, hipStream_t stream) {
    const size_t N = N_NODES, E = N_EDGES, G = NUM_GRAPHS;
    const float* x = (const float*)d_in[0];
    const float* ea = (const float*)d_in[1];
    const int* ei = (const int*)d_in[2];
    const int* srcv = ei;
    const int* dstv = ei + E;
    const int* batch = (const int*)d_in[3];
    const float* Wn = (const float*)d_in[5];  const float* bn_ = (const float*)d_in[6];
    const float* We = (const float*)d_in[7];  const float* be_ = (const float*)d_in[8];
    const float* W1a = (const float*)d_in[9]; const float* b1a = (const float*)d_in[10];
    const float* W1b = (const float*)d_in[11]; const float* b1b = (const float*)d_in[12];
    const float* W2a = (const float*)d_in[13]; const float* b2a = (const float*)d_in[14];
    const float* W2b = (const float*)d_in[15]; const float* b2b = (const float*)d_in[16];
    const float* W3a = (const float*)d_in[17]; const float* b3a = (const float*)d_in[18];
    const float* W3b = (const float*)d_in[19]; const float* b3b = (const float*)d_in[20];
    const float* g1 = (const float*)d_in[21]; const float* be1 = (const float*)d_in[22];
    const float* g2 = (const float*)d_in[23]; const float* be2 = (const float*)d_in[24];
    const float* g3 = (const float*)d_in[25]; const float* be3 = (const float*)d_in[26];
    const float* Wfc = (const float*)d_in[27]; const float* bfc = (const float*)d_in[28];

    size_t off = 0;
    auto take = [&](size_t bytes) { size_t o = off; off += (bytes + 255) & ~(size_t)255; return o; };
    int* hist = (int*)(base + take(N * 4));
    float* hbuf = (float*)(base + take(N * 64 * 4));
    ST* Pd = (ST*)(base + take(N * 128 * sizeof(ST)));
    ST* Ps = (ST*)(base + take(N * 128 * sizeof(ST)));
    float* Abuf = (float*)(base + take(N * 128 * 4));
    u16* e16 = (u16*)(base + take(E * 16 * 2));
    float* stats = (float*)(base + take(256 * 4));
    float* pool = (float*)(base + take(G * 16 * 4));
    int* gcnt = (int*)(base + take(G * 4));

    hipMemsetAsync(hist, 0, N * 4, stream);
    hist_k<<<dim3((E + 255) / 256), dim3(256), 0, stream>>>(dstv, hist);

    edge_emb_k<<<dim3((E * 16 + 255) / 256), dim3(256), 0, stream>>>(ea, We, be_, e16);
    node_emb_k<<<dim3((N * 64 + 255) / 256), dim3(256), 0, stream>>>(x, Wn, bn_, hbuf);

    // conv1: F=64, H=128, Fo=64, edge rows of W1a start at 128
    proj_k<64, 128, ST><<<dim3((N * 128 + 255) / 256), dim3(256), 0, stream>>>(hbuf, W1a, b1a, Pd, Ps);
    hipMemsetAsync(Abuf, 0, N * 128 * 4, stream);
    eagg_k<128, ST><<<dim3((unsigned)((E * 128 + 255) / 256)), dim3(256), 0, stream>>>(srcv, dstv, e16, Pd, Ps, W1a, 128, Abuf);
    ymlp_k<128, 64><<<dim3((N * 64 + 255) / 256), dim3(256), 0, stream>>>(Abuf, hist, W1b, b1b, hbuf);
    stats_k<64><<<dim3(64), dim3(256), 0, stream>>>(hbuf, stats);
    bnrelu_k<64><<<dim3((N * 64 + 255) / 256), dim3(256), 0, stream>>>(hbuf, stats, g1, be1);

    // conv2: F=64, H=64, Fo=32, edge rows of W2a start at 128
    proj_k<64, 64, ST><<<dim3((N * 64 + 255) / 256), dim3(256), 0, stream>>>(hbuf, W2a, b2a, Pd, Ps);
    hipMemsetAsync(Abuf, 0, N * 64 * 4, stream);
    eagg_k<64, ST><<<dim3((unsigned)((E * 64 + 255) / 256)), dim3(256), 0, stream>>>(srcv, dstv, e16, Pd, Ps, W2a, 128, Abuf);
    ymlp_k<64, 32><<<dim3((N * 32 + 255) / 256), dim3(256), 0, stream>>>(Abuf, hist, W2b, b2b, hbuf);
    stats_k<32><<<dim3(32), dim3(256), 0, stream>>>(hbuf, stats);
    bnrelu_k<32><<<dim3((N * 32 + 255) / 256), dim3(256), 0, stream>>>(hbuf, stats, g2, be2);

    // conv3: F=32, H=32, Fo=16, edge rows of W3a start at 64
    proj_k<32, 32, ST><<<dim3((N * 32 + 255) / 256), dim3(256), 0, stream>>>(hbuf, W3a, b3a, Pd, Ps);
    hipMemsetAsync(Abuf, 0, N * 32 * 4, stream);
    eagg_k<32, ST><<<dim3((unsigned)((E * 32 + 255) / 256)), dim3(256), 0, stream>>>(srcv, dstv, e16, Pd, Ps, W3a, 64, Abuf);
    ymlp_k<32, 16><<<dim3((N * 16 + 255) / 256), dim3(256), 0, stream>>>(Abuf, hist, W3b, b3b, hbuf);
    stats_k<16><<<dim3(16), dim3(256), 0, stream>>>(hbuf, stats);
    bnrelu_k<16><<<dim3((N * 16 + 255) / 256), dim3(256), 0, stream>>>(hbuf, stats, g3, be3);

    hipMemsetAsync(pool, 0, G * 16 * 4, stream);
    hipMemsetAsync(gcnt, 0, G * 4, stream);
    pool_k<<<dim3((N * 16 + 255) / 256), dim3(256), 0, stream>>>(hbuf, batch, pool, gcnt);
    out_k<<<dim3((G * 12 + 255) / 256), dim3(256), 0, stream>>>(pool, gcnt, Wfc, bfc, (float*)d_out);
}

extern "C" void kernel_launch(void* const* d_in, const int* in_sizes, int n_in,
                              void* d_out, int out_size, void* d_ws, size_t ws_size,
                              hipStream_t stream) {
    const size_t N = N_NODES, E = N_EDGES, G = NUM_GRAPHS;
    auto need = [&](size_t stbytes) {
        size_t o = 0;
        auto take = [&](size_t b) { o += (b + 255) & ~(size_t)255; };
        take(N * 4); take(N * 64 * 4);
        take(N * 128 * stbytes); take(N * 128 * stbytes);
        take(N * 128 * 4); take(E * 16 * 2);
        take(256 * 4); take(G * 16 * 4); take(G * 4);
        return o;
    };
    if (ws_size >= need(4)) {
        run_pipeline<float>(d_in, d_out, (char*)d_ws, stream);   // fp32 staging (preferred)
    } else if (ws_size >= need(2)) {
        run_pipeline<u16>(d_in, d_out, (char*)d_ws, stream);     // bf16 staging fallback
    } else {
        fprintf(stderr, "kernel_launch: ws too small: need %zu have %zu\n", need(2), ws_size);
    }
}

// Round 7
// 2366.222 us; speedup vs baseline: 1.2029x; 1.2029x over previous
//
#include <hip/hip_runtime.h>
#include <hip/hip_bf16.h>
#include <cstdio>

// GCNTox21 — round 7: CSR gather + fused agg/ymlp conv kernel.
// Round-6 counters: eagg atomics dominated (820us conv1, HBM 26%, VALU 39%).
// Now: one wave per node gathers edges (no atomics), computes mean in regs,
// and applies the Wb mat-vec in-wave via __shfl + LDS Wb. CSR built per call.

#define N_NODES 100000
#define N_EDGES 1600000
#define NUM_GRAPHS 4096

typedef unsigned short u16;
typedef unsigned int u32;

__device__ __forceinline__ float b2f(u16 u) { union { u32 i; float f; } c; c.i = ((u32)u) << 16; return c.f; }
__device__ __forceinline__ float b2f_lo(u32 u) { union { u32 i; float f; } c; c.i = u << 16; return c.f; }
__device__ __forceinline__ float b2f_hi(u32 u) { union { u32 i; float f; } c; c.i = u & 0xffff0000u; return c.f; }
__device__ __forceinline__ u16 f2b(float f) {
    __hip_bfloat16 h = __float2bfloat16(f);
    return *reinterpret_cast<u16*>(&h);
}

template <typename ST> __device__ __forceinline__ void st_store(ST* p, float v);
template <> __device__ __forceinline__ void st_store<float>(float* p, float v) { *p = v; }
template <> __device__ __forceinline__ void st_store<u16>(u16* p, float v) { *p = f2b(v); }
template <typename ST> __device__ __forceinline__ float st_load(const ST* p);
template <> __device__ __forceinline__ float st_load<float>(const float* p) { return *p; }
template <> __device__ __forceinline__ float st_load<u16>(const u16* p) { return b2f(*p); }

// ---------------- CSR build ----------------
__global__ __launch_bounds__(256) void hist_k(const int* __restrict__ dst, int* __restrict__ hist) {
    int e = blockIdx.x * 256 + threadIdx.x;
    if (e < N_EDGES) atomicAdd(&hist[dst[e]], 1);
}

// two-level scan: block-local (1024 elems/block) -> block sums
__global__ __launch_bounds__(256) void scan_part_k(const int* __restrict__ hist,
        int* __restrict__ excl, int* __restrict__ bsum) {
    __shared__ int sm[256];
    int t = threadIdx.x, b = blockIdx.x;
    int base = b * 1024 + t * 4;
    int v0 = (base + 0 < N_NODES) ? hist[base + 0] : 0;
    int v1 = (base + 1 < N_NODES) ? hist[base + 1] : 0;
    int v2 = (base + 2 < N_NODES) ? hist[base + 2] : 0;
    int v3 = (base + 3 < N_NODES) ? hist[base + 3] : 0;
    int tsum = v0 + v1 + v2 + v3;
    sm[t] = tsum;
    __syncthreads();
    for (int o = 1; o < 256; o <<= 1) {
        int x = (t >= o) ? sm[t - o] : 0;
        __syncthreads();
        sm[t] += x;
        __syncthreads();
    }
    int texcl = sm[t] - tsum;
    if (base + 0 < N_NODES) excl[base + 0] = texcl;
    if (base + 1 < N_NODES) excl[base + 1] = texcl + v0;
    if (base + 2 < N_NODES) excl[base + 2] = texcl + v0 + v1;
    if (base + 3 < N_NODES) excl[base + 3] = texcl + v0 + v1 + v2;
    if (t == 255) bsum[b] = sm[255];
}

__global__ __launch_bounds__(256) void scan_top_k(int* __restrict__ bsum, int* __restrict__ boff,
        int nb, int* __restrict__ row_ptr_last) {
    __shared__ int sm[256];
    int t = threadIdx.x;
    int v = (t < nb) ? bsum[t] : 0;
    sm[t] = v;
    __syncthreads();
    for (int o = 1; o < 256; o <<= 1) {
        int x = (t >= o) ? sm[t - o] : 0;
        __syncthreads();
        sm[t] += x;
        __syncthreads();
    }
    if (t < nb) boff[t] = sm[t] - v;
    if (t == 0) *row_ptr_last = sm[255];   // == N_EDGES
}

__global__ __launch_bounds__(256) void scan_add_k(int* __restrict__ excl, const int* __restrict__ boff,
        int* __restrict__ row_ptr, int* __restrict__ cursor) {
    int i = blockIdx.x * 256 + threadIdx.x;
    if (i >= N_NODES) return;
    int s = excl[i] + boff[i >> 10];
    row_ptr[i] = s;
    cursor[i] = s;
}

__global__ __launch_bounds__(256) void scatter_k(const int* __restrict__ dst,
        int* __restrict__ cursor, int* __restrict__ sorted_eid) {
    int e = blockIdx.x * 256 + threadIdx.x;
    if (e < N_EDGES) {
        int p = atomicAdd(&cursor[dst[e]], 1);
        sorted_eid[p] = e;
    }
}

// ---------------- embeddings ----------------
__global__ __launch_bounds__(256) void edge_emb_k(const float* __restrict__ ea,
        const float* __restrict__ We, const float* __restrict__ be, u16* __restrict__ e16) {
    int idx = blockIdx.x * 256 + threadIdx.x;
    if (idx >= N_EDGES * 16) return;
    int e = idx >> 4, k = idx & 15;
    float acc = be[k];
#pragma unroll
    for (int j = 0; j < 8; ++j) acc += ea[(size_t)e * 8 + j] * We[j * 16 + k];
    e16[idx] = f2b(fmaxf(acc, 0.f));
}

__global__ __launch_bounds__(256) void node_emb_k(const float* __restrict__ x,
        const float* __restrict__ Wn, const float* __restrict__ bn_, float* __restrict__ h) {
    int idx = blockIdx.x * 256 + threadIdx.x;
    if (idx >= N_NODES * 64) return;
    int v = idx >> 6, c = idx & 63;
    float acc = bn_[c];
    for (int k = 0; k < 32; ++k) acc += x[(size_t)v * 32 + k] * Wn[(size_t)k * 64 + c];
    h[idx] = fmaxf(acc, 0.f);
}

// ---------------- projections ----------------
template <int F, int H, typename ST>
__global__ __launch_bounds__(256) void proj_k(const float* __restrict__ h,
        const float* __restrict__ Wa, const float* __restrict__ ba,
        ST* __restrict__ Pd, ST* __restrict__ Ps) {
    int idx = blockIdx.x * 256 + threadIdx.x;
    if (idx >= N_NODES * H) return;
    int v = idx / H, c = idx % H;
    float ad = ba[c], as = 0.f;
    const float* hr = h + (size_t)v * F;
    for (int k = 0; k < F; ++k) {
        float hk = hr[k];
        ad += hk * Wa[(size_t)k * H + c];
        as += hk * Wa[(size_t)(F + k) * H + c];
    }
    st_store(&Pd[idx], ad);
    st_store(&Ps[idx], as);
}

// ---------------- fused conv: CSR gather + mean + Wb mat-vec ----------------
// wave per node; lane holds CPL channels. A[v][c] = sum_e relu(Pd[v][c] +
// Ps[src][c] + e16[e].W16[:,c]); y[v] = (A/deg)@Wb + bb (deg>0 else 0).
template <int H, int Fo, typename ST>
__global__ __launch_bounds__(256) void conv_k(
        const int* __restrict__ row_ptr, const int* __restrict__ sorted_eid,
        const int* __restrict__ src, const u16* __restrict__ e16,
        const ST* __restrict__ Pd, const ST* __restrict__ Ps,
        const float* __restrict__ Wae, const float* __restrict__ Wb,
        const float* __restrict__ bb, float* __restrict__ y) {
    constexpr int CPL = (H >= 64) ? H / 64 : 1;
    __shared__ float Wb_sh[H * Fo];
    for (int i = threadIdx.x; i < H * Fo; i += 256) Wb_sh[i] = Wb[i];
    __syncthreads();
    const int wave = threadIdx.x >> 6, lane = threadIdx.x & 63;
    int v = blockIdx.x * 4 + wave;
    if (v >= N_NODES) v = N_NODES - 1;           // duplicate work, benign same-value store
    const int c0 = (lane * CPL < H) ? lane * CPL : (H - CPL);
    float w16[16][CPL];
#pragma unroll
    for (int k = 0; k < 16; ++k)
#pragma unroll
        for (int j = 0; j < CPL; ++j) w16[k][j] = Wae[k * H + c0 + j];
    float pd[CPL], acc[CPL];
#pragma unroll
    for (int j = 0; j < CPL; ++j) {
        pd[j] = st_load(&Pd[(size_t)v * H + c0 + j]);
        acc[j] = 0.f;
    }
    const int p0 = row_ptr[v], p1 = row_ptr[v + 1];
    for (int p = p0; p < p1; ++p) {
        int e = sorted_eid[p];
        int s = src[e];
        const uint4* er = (const uint4*)(e16 + (size_t)e * 16);
        uint4 r0 = er[0], r1 = er[1];
        float ev[16];
        ev[0] = b2f_lo(r0.x); ev[1] = b2f_hi(r0.x); ev[2] = b2f_lo(r0.y); ev[3] = b2f_hi(r0.y);
        ev[4] = b2f_lo(r0.z); ev[5] = b2f_hi(r0.z); ev[6] = b2f_lo(r0.w); ev[7] = b2f_hi(r0.w);
        ev[8] = b2f_lo(r1.x); ev[9] = b2f_hi(r1.x); ev[10] = b2f_lo(r1.y); ev[11] = b2f_hi(r1.y);
        ev[12] = b2f_lo(r1.z); ev[13] = b2f_hi(r1.z); ev[14] = b2f_lo(r1.w); ev[15] = b2f_hi(r1.w);
        float z[CPL];
#pragma unroll
        for (int j = 0; j < CPL; ++j) z[j] = pd[j] + st_load(&Ps[(size_t)s * H + c0 + j]);
#pragma unroll
        for (int k = 0; k < 16; ++k)
#pragma unroll
            for (int j = 0; j < CPL; ++j) z[j] += ev[k] * w16[k][j];
#pragma unroll
        for (int j = 0; j < CPL; ++j) acc[j] += fmaxf(z[j], 0.f);
    }
    const int deg = p1 - p0;
    const float invd = (deg > 0) ? 1.f / (float)deg : 0.f;
    float m[CPL];
#pragma unroll
    for (int j = 0; j < CPL; ++j) m[j] = acc[j] * invd;
    const int co = (lane < Fo) ? lane : 0;
    float yv = 0.f;
#pragma unroll
    for (int k = 0; k < H; ++k)
        yv += __shfl(m[k % CPL], k / CPL) * Wb_sh[k * Fo + co];
    if (lane < Fo)
        y[(size_t)v * Fo + lane] = (deg > 0) ? (yv + bb[lane]) : 0.f;
}

// ---------------- BN stats (coalesced, LDS pre-reduce, atomic finish) ----------------
template <int Fo>
__global__ __launch_bounds__(256) void stats2_k(const float* __restrict__ y, float* __restrict__ stats) {
    __shared__ float sh[2 * Fo];
    for (int i = threadIdx.x; i < 2 * Fo; i += 256) sh[i] = 0.f;
    __syncthreads();
    const int co = threadIdx.x % Fo;   // stride (grid*256) is a multiple of Fo
    float s1 = 0.f, s2 = 0.f;
    const long long total = (long long)N_NODES * Fo;
    for (long long i = (long long)blockIdx.x * 256 + threadIdx.x; i < total; i += (long long)gridDim.x * 256) {
        float v = y[i];
        s1 += v; s2 += v * v;
    }
    atomicAdd(&sh[co], s1);
    atomicAdd(&sh[Fo + co], s2);
    __syncthreads();
    if (threadIdx.x < 2 * Fo) atomicAdd(&stats[threadIdx.x], sh[threadIdx.x]);
}

template <int Fo>
__global__ __launch_bounds__(256) void bnrelu_k(float* __restrict__ y,
        const float* __restrict__ stats, const float* __restrict__ g, const float* __restrict__ beta) {
    int idx = blockIdx.x * 256 + threadIdx.x;
    if (idx >= N_NODES * Fo) return;
    int co = idx % Fo;
    const float invN = 1.0f / (float)N_NODES;
    float mu = stats[co] * invN;
    float ex2 = stats[Fo + co] * invN;
    float var = fmaxf(ex2 - mu * mu, 0.f);
    float rs = rsqrtf(var + 1e-5f);
    y[idx] = fmaxf((y[idx] - mu) * rs * g[co] + beta[co], 0.f);
}

// ---------------- pooling & head ----------------
__global__ __launch_bounds__(256) void pool_k(const float* __restrict__ h,
        const int* __restrict__ batch, float* __restrict__ pool, int* __restrict__ gcnt) {
    int idx = blockIdx.x * 256 + threadIdx.x;
    if (idx >= N_NODES * 16) return;
    int v = idx >> 4, c = idx & 15;
    int b = batch[v];
    atomicAdd(&pool[b * 16 + c], h[idx]);
    if (c == 0) atomicAdd(&gcnt[b], 1);
}

__global__ __launch_bounds__(256) void out_k(const float* __restrict__ pool,
        const int* __restrict__ gcnt, const float* __restrict__ Wfc,
        const float* __restrict__ bfc, float* __restrict__ out) {
    int idx = blockIdx.x * 256 + threadIdx.x;
    if (idx >= NUM_GRAPHS * 12) return;
    int g = idx / 12, o = idx % 12;
    int cnt = gcnt[g];
    float inv = 1.0f / (float)(cnt > 0 ? cnt : 1);
    float acc = bfc[o];
#pragma unroll
    for (int k = 0; k < 16; ++k) acc += pool[g * 16 + k] * inv * Wfc[k * 12 + o];
    out[idx] = 1.0f / (1.0f + expf(-acc));
}

template <typename ST>
static void run_pipeline(void* const* d_in, void* d_out, char* base, hipStream_t stream) {
    const size_t N = N_NODES, E = N_EDGES, G = NUM_GRAPHS;
    const float* x = (const float*)d_in[0];
    const float* ea = (const float*)d_in[1];
    const int* ei = (const int*)d_in[2];
    const int* srcv = ei;
    const int* dstv = ei + E;
    const int* batch = (const int*)d_in[3];
    const float* Wn = (const float*)d_in[5];  const float* bn_ = (const float*)d_in[6];
    const float* We = (const float*)d_in[7];  const float* be_ = (const float*)d_in[8];
    const float* W1a = (const float*)d_in[9]; const float* b1a = (const float*)d_in[10];
    const float* W1b = (const float*)d_in[11]; const float* b1b = (const float*)d_in[12];
    const float* W2a = (const float*)d_in[13]; const float* b2a = (const float*)d_in[14];
    const float* W2b = (const float*)d_in[15]; const float* b2b = (const float*)d_in[16];
    const float* W3a = (const float*)d_in[17]; const float* b3a = (const float*)d_in[18];
    const float* W3b = (const float*)d_in[19]; const float* b3b = (const float*)d_in[20];
    const float* g1 = (const float*)d_in[21]; const float* be1 = (const float*)d_in[22];
    const float* g2 = (const float*)d_in[23]; const float* be2 = (const float*)d_in[24];
    const float* g3 = (const float*)d_in[25]; const float* be3 = (const float*)d_in[26];
    const float* Wfc = (const float*)d_in[27]; const float* bfc = (const float*)d_in[28];

    size_t off = 0;
    auto take = [&](size_t bytes) { size_t o = off; off += (bytes + 255) & ~(size_t)255; return o; };
    int* hist = (int*)(base + take(N * 4));
    int* cursor = (int*)(base + take(N * 4));
    int* row_ptr = (int*)(base + take((N + 1) * 4));
    int* bsum = (int*)(base + take(256 * 4));
    int* boff = (int*)(base + take(256 * 4));
    int* sorted = (int*)(base + take(E * 4));
    float* hbuf = (float*)(base + take(N * 64 * 4));
    ST* Pd = (ST*)(base + take(N * 128 * sizeof(ST)));
    ST* Ps = (ST*)(base + take(N * 128 * sizeof(ST)));
    u16* e16 = (u16*)(base + take(E * 16 * 2));
    float* stats = (float*)(base + take(256 * 4));
    float* pool = (float*)(base + take(G * 16 * 4));
    int* gcnt = (int*)(base + take(G * 4));

    const int NB = (N_NODES + 1023) / 1024;   // 98 scan blocks

    // CSR build
    hipMemsetAsync(hist, 0, N * 4, stream);
    hist_k<<<dim3((E + 255) / 256), dim3(256), 0, stream>>>(dstv, hist);
    scan_part_k<<<dim3(NB), dim3(256), 0, stream>>>(hist, cursor /*excl tmp*/, bsum);
    scan_top_k<<<dim3(1), dim3(256), 0, stream>>>(bsum, boff, NB, &row_ptr[N_NODES]);
    scan_add_k<<<dim3((N + 255) / 256), dim3(256), 0, stream>>>(cursor, boff, row_ptr, cursor);
    scatter_k<<<dim3((E + 255) / 256), dim3(256), 0, stream>>>(dstv, cursor, sorted);

    // embeddings
    edge_emb_k<<<dim3((E * 16 + 255) / 256), dim3(256), 0, stream>>>(ea, We, be_, e16);
    node_emb_k<<<dim3((N * 64 + 255) / 256), dim3(256), 0, stream>>>(x, Wn, bn_, hbuf);

    const unsigned cgrid = (N_NODES + 3) / 4;

    // conv1: F=64, H=128, Fo=64 (edge rows of W1a at 128)
    proj_k<64, 128, ST><<<dim3((N * 128 + 255) / 256), dim3(256), 0, stream>>>(hbuf, W1a, b1a, Pd, Ps);
    conv_k<128, 64, ST><<<dim3(cgrid), dim3(256), 0, stream>>>(row_ptr, sorted, srcv, e16, Pd, Ps,
            W1a + 128 * 128, W1b, b1b, hbuf);
    hipMemsetAsync(stats, 0, 256 * 4, stream);
    stats2_k<64><<<dim3(512), dim3(256), 0, stream>>>(hbuf, stats);
    bnrelu_k<64><<<dim3((N * 64 + 255) / 256), dim3(256), 0, stream>>>(hbuf, stats, g1, be1);

    // conv2: F=64, H=64, Fo=32 (edge rows of W2a at 128)
    proj_k<64, 64, ST><<<dim3((N * 64 + 255) / 256), dim3(256), 0, stream>>>(hbuf, W2a, b2a, Pd, Ps);
    conv_k<64, 32, ST><<<dim3(cgrid), dim3(256), 0, stream>>>(row_ptr, sorted, srcv, e16, Pd, Ps,
            W2a + 128 * 64, W2b, b2b, hbuf);
    hipMemsetAsync(stats, 0, 256 * 4, stream);
    stats2_k<32><<<dim3(512), dim3(256), 0, stream>>>(hbuf, stats);
    bnrelu_k<32><<<dim3((N * 32 + 255) / 256), dim3(256), 0, stream>>>(hbuf, stats, g2, be2);

    // conv3: F=32, H=32, Fo=16 (edge rows of W3a at 64)
    proj_k<32, 32, ST><<<dim3((N * 32 + 255) / 256), dim3(256), 0, stream>>>(hbuf, W3a, b3a, Pd, Ps);
    conv_k<32, 16, ST><<<dim3(cgrid), dim3(256), 0, stream>>>(row_ptr, sorted, srcv, e16, Pd, Ps,
            W3a + 64 * 32, W3b, b3b, hbuf);
    hipMemsetAsync(stats, 0, 256 * 4, stream);
    stats2_k<16><<<dim3(512), dim3(256), 0, stream>>>(hbuf, stats);
    bnrelu_k<16><<<dim3((N * 16 + 255) / 256), dim3(256), 0, stream>>>(hbuf, stats, g3, be3);

    // pool + head
    hipMemsetAsync(pool, 0, G * 16 * 4, stream);
    hipMemsetAsync(gcnt, 0, G * 4, stream);
    pool_k<<<dim3((N * 16 + 255) / 256), dim3(256), 0, stream>>>(hbuf, batch, pool, gcnt);
    out_k<<<dim3((G * 12 + 255) / 256), dim3(256), 0, stream>>>(pool, gcnt, Wfc, bfc, (float*)d_out);
}

extern "C" void kernel_launch(void* const* d_in, const int* in_sizes, int n_in,
                              void* d_out, int out_size, void* d_ws, size_t ws_size,
                              hipStream_t stream) {
    const size_t N = N_NODES, E = N_EDGES, G = NUM_GRAPHS;
    auto need = [&](size_t stbytes) {
        size_t o = 0;
        auto take = [&](size_t b) { o += (b + 255) & ~(size_t)255; };
        take(N * 4); take(N * 4); take((N + 1) * 4); take(256 * 4); take(256 * 4);
        take(E * 4); take(N * 64 * 4);
        take(N * 128 * stbytes); take(N * 128 * stbytes);
        take(E * 16 * 2);
        take(256 * 4); take(G * 16 * 4); take(G * 4);
        return o;
    };
    if (ws_size >= need(4)) {
        run_pipeline<float>(d_in, d_out, (char*)d_ws, stream);   // fp32 staging
    } else if (ws_size >= need(2)) {
        run_pipeline<u16>(d_in, d_out, (char*)d_ws, stream);     // bf16 staging fallback
    } else {
        fprintf(stderr, "kernel_launch: ws too small: need %zu have %zu\n", need(2), ws_size);
    }
}

// Round 8
// 2338.934 us; speedup vs baseline: 1.2169x; 1.0117x over previous
//
#include <hip/hip_runtime.h>
#include <hip/hip_bf16.h>
#include <cstdio>

// GCNTox21 — round 8. conv_k was latency-bound (VALU 33%, HBM 11%, occ 29%):
// (1) edge data (srcs, e16) stored in CSR order -> no indirection, sequential
//     reads; only Ps[src] row gather stays random (coalesced 512B).
// (2) persistent grid-stride blocks: Wb_sh loaded once per block (was once
//     per 4 nodes -> ~800MB of L2 traffic, the round-7 FETCH_SIZE).
// (3) 1-deep software pipeline in the edge loop (prefetch srcs/e16/Ps).
// (4) H=32: two nodes per wave.

#define N_NODES 100000
#define N_EDGES 1600000
#define NUM_GRAPHS 4096

typedef unsigned short u16;
typedef unsigned int u32;

__device__ __forceinline__ float b2f(u16 u) { union { u32 i; float f; } c; c.i = ((u32)u) << 16; return c.f; }
__device__ __forceinline__ float b2f_lo(u32 u) { union { u32 i; float f; } c; c.i = u << 16; return c.f; }
__device__ __forceinline__ float b2f_hi(u32 u) { union { u32 i; float f; } c; c.i = u & 0xffff0000u; return c.f; }
__device__ __forceinline__ u16 f2b(float f) {
    __hip_bfloat16 h = __float2bfloat16(f);
    return *reinterpret_cast<u16*>(&h);
}

template <typename ST> __device__ __forceinline__ void st_store(ST* p, float v);
template <> __device__ __forceinline__ void st_store<float>(float* p, float v) { *p = v; }
template <> __device__ __forceinline__ void st_store<u16>(u16* p, float v) { *p = f2b(v); }
template <typename ST> __device__ __forceinline__ float st_load(const ST* p);
template <> __device__ __forceinline__ float st_load<float>(const float* p) { return *p; }
template <> __device__ __forceinline__ float st_load<u16>(const u16* p) { return b2f(*p); }

// load CPL consecutive staged values starting at base (c0-aligned)
template <typename ST, int CPL>
__device__ __forceinline__ void ld_row(const ST* base, float out[CPL]) {
    if constexpr (CPL == 1) {
        out[0] = st_load(base);
    } else {
        if constexpr (sizeof(ST) == 4) {
            float2 v = *(const float2*)base;
            out[0] = v.x; out[1] = v.y;
        } else {
            u32 v = *(const u32*)base;
            out[0] = b2f_lo(v); out[1] = b2f_hi(v);
        }
    }
}

// ---------------- CSR build ----------------
__global__ __launch_bounds__(256) void hist_k(const int* __restrict__ dst, int* __restrict__ hist) {
    int e = blockIdx.x * 256 + threadIdx.x;
    if (e < N_EDGES) atomicAdd(&hist[dst[e]], 1);
}

__global__ __launch_bounds__(256) void scan_part_k(const int* __restrict__ hist,
        int* __restrict__ excl, int* __restrict__ bsum) {
    __shared__ int sm[256];
    int t = threadIdx.x, b = blockIdx.x;
    int base = b * 1024 + t * 4;
    int v0 = (base + 0 < N_NODES) ? hist[base + 0] : 0;
    int v1 = (base + 1 < N_NODES) ? hist[base + 1] : 0;
    int v2 = (base + 2 < N_NODES) ? hist[base + 2] : 0;
    int v3 = (base + 3 < N_NODES) ? hist[base + 3] : 0;
    int tsum = v0 + v1 + v2 + v3;
    sm[t] = tsum;
    __syncthreads();
    for (int o = 1; o < 256; o <<= 1) {
        int x = (t >= o) ? sm[t - o] : 0;
        __syncthreads();
        sm[t] += x;
        __syncthreads();
    }
    int texcl = sm[t] - tsum;
    if (base + 0 < N_NODES) excl[base + 0] = texcl;
    if (base + 1 < N_NODES) excl[base + 1] = texcl + v0;
    if (base + 2 < N_NODES) excl[base + 2] = texcl + v0 + v1;
    if (base + 3 < N_NODES) excl[base + 3] = texcl + v0 + v1 + v2;
    if (t == 255) bsum[b] = sm[255];
}

__global__ __launch_bounds__(256) void scan_top_k(int* __restrict__ bsum, int* __restrict__ boff,
        int nb, int* __restrict__ row_ptr_last) {
    __shared__ int sm[256];
    int t = threadIdx.x;
    int v = (t < nb) ? bsum[t] : 0;
    sm[t] = v;
    __syncthreads();
    for (int o = 1; o < 256; o <<= 1) {
        int x = (t >= o) ? sm[t - o] : 0;
        __syncthreads();
        sm[t] += x;
        __syncthreads();
    }
    if (t < nb) boff[t] = sm[t] - v;
    if (t == 0) *row_ptr_last = sm[255];
}

__global__ __launch_bounds__(256) void scan_add_k(int* __restrict__ excl, const int* __restrict__ boff,
        int* __restrict__ row_ptr, int* __restrict__ cursor) {
    int i = blockIdx.x * 256 + threadIdx.x;
    if (i >= N_NODES) return;
    int s = excl[i] + boff[i >> 10];
    row_ptr[i] = s;
    cursor[i] = s;
}

// also writes srcs (src node of each sorted slot)
__global__ __launch_bounds__(256) void scatter_k(const int* __restrict__ src, const int* __restrict__ dst,
        int* __restrict__ cursor, int* __restrict__ sorted_eid, int* __restrict__ srcs) {
    int e = blockIdx.x * 256 + threadIdx.x;
    if (e < N_EDGES) {
        int p = atomicAdd(&cursor[dst[e]], 1);
        sorted_eid[p] = e;
        srcs[p] = src[e];
    }
}

// ---------------- embeddings ----------------
// e16s[p][k] = relu(edge_attr[sorted_eid[p]] @ We + be), bf16, CSR order
__global__ __launch_bounds__(256) void edge_emb_k(const float* __restrict__ ea,
        const float* __restrict__ We, const float* __restrict__ be,
        const int* __restrict__ sorted_eid, u16* __restrict__ e16s) {
    int idx = blockIdx.x * 256 + threadIdx.x;
    if (idx >= N_EDGES * 16) return;
    int p = idx >> 4, k = idx & 15;
    int e = sorted_eid[p];
    float acc = be[k];
#pragma unroll
    for (int j = 0; j < 8; ++j) acc += ea[(size_t)e * 8 + j] * We[j * 16 + k];
    e16s[idx] = f2b(fmaxf(acc, 0.f));
}

__global__ __launch_bounds__(256) void node_emb_k(const float* __restrict__ x,
        const float* __restrict__ Wn, const float* __restrict__ bn_, float* __restrict__ h) {
    int idx = blockIdx.x * 256 + threadIdx.x;
    if (idx >= N_NODES * 64) return;
    int v = idx >> 6, c = idx & 63;
    float acc = bn_[c];
    for (int k = 0; k < 32; ++k) acc += x[(size_t)v * 32 + k] * Wn[(size_t)k * 64 + c];
    h[idx] = fmaxf(acc, 0.f);
}

// ---------------- projections ----------------
template <int F, int H, typename ST>
__global__ __launch_bounds__(256) void proj_k(const float* __restrict__ h,
        const float* __restrict__ Wa, const float* __restrict__ ba,
        ST* __restrict__ Pd, ST* __restrict__ Ps) {
    int idx = blockIdx.x * 256 + threadIdx.x;
    if (idx >= N_NODES * H) return;
    int v = idx / H, c = idx % H;
    float ad = ba[c], as = 0.f;
    const float* hr = h + (size_t)v * F;
    for (int k = 0; k < F; ++k) {
        float hk = hr[k];
        ad += hk * Wa[(size_t)k * H + c];
        as += hk * Wa[(size_t)(F + k) * H + c];
    }
    st_store(&Pd[idx], ad);
    st_store(&Ps[idx], as);
}

// ---------------- fused conv: CSR gather + mean + Wb mat-vec ----------------
template <int H, int Fo, typename ST>
__global__ __launch_bounds__(256) void conv_k(
        const int* __restrict__ row_ptr, const int* __restrict__ srcs,
        const u16* __restrict__ e16s,
        const ST* __restrict__ Pd, const ST* __restrict__ Ps,
        const float* __restrict__ Wae, const float* __restrict__ Wb,
        const float* __restrict__ bb, float* __restrict__ y) {
    constexpr int SL = (H >= 64) ? 64 : 32;   // lanes per node
    constexpr int NPW = 64 / SL;              // nodes per wave
    constexpr int CPL = H / SL;               // channels per lane (1 or 2)
    constexpr int NPB = 4 * NPW;              // nodes per block per iter
    __shared__ float Wb_sh[H * Fo];
    for (int i = threadIdx.x; i < H * Fo; i += 256) Wb_sh[i] = Wb[i];
    __syncthreads();
    const int wave = threadIdx.x >> 6, lane = threadIdx.x & 63;
    const int sub = lane / SL;                // node slot within wave
    const int sl = lane % SL;
    const int c0 = sl * CPL;
    float w16[16][CPL];
#pragma unroll
    for (int k = 0; k < 16; ++k)
#pragma unroll
        for (int j = 0; j < CPL; ++j) w16[k][j] = Wae[k * H + c0 + j];

    for (int v = blockIdx.x * NPB + wave * NPW + sub; v < N_NODES; v += gridDim.x * NPB) {
        float pd[CPL], acc[CPL];
        ld_row<ST, CPL>(&Pd[(size_t)v * H + c0], pd);
#pragma unroll
        for (int j = 0; j < CPL; ++j) acc[j] = 0.f;
        const int p0 = row_ptr[v], p1 = row_ptr[v + 1];
        const int deg = p1 - p0;
        if (deg > 0) {
            // software pipeline: prefetch slot "n" (next), compute slot "c"
            int s_n = srcs[p0];
            const uint4* ern = (const uint4*)(e16s + (size_t)p0 * 16);
            uint4 r0n = ern[0], r1n = ern[1];
            float psn[CPL];
            ld_row<ST, CPL>(&Ps[(size_t)s_n * H + c0], psn);
            for (int p = p0; p < p1; ++p) {
                float psc[CPL];
                uint4 r0c = r0n, r1c = r1n;
#pragma unroll
                for (int j = 0; j < CPL; ++j) psc[j] = psn[j];
                int q = (p + 1 < p1) ? (p + 1) : p;
                int s_q = srcs[q];
                const uint4* erq = (const uint4*)(e16s + (size_t)q * 16);
                r0n = erq[0]; r1n = erq[1];
                ld_row<ST, CPL>(&Ps[(size_t)s_q * H + c0], psn);
                // compute current edge
                float ev[16];
                ev[0] = b2f_lo(r0c.x); ev[1] = b2f_hi(r0c.x); ev[2] = b2f_lo(r0c.y); ev[3] = b2f_hi(r0c.y);
                ev[4] = b2f_lo(r0c.z); ev[5] = b2f_hi(r0c.z); ev[6] = b2f_lo(r0c.w); ev[7] = b2f_hi(r0c.w);
                ev[8] = b2f_lo(r1c.x); ev[9] = b2f_hi(r1c.x); ev[10] = b2f_lo(r1c.y); ev[11] = b2f_hi(r1c.y);
                ev[12] = b2f_lo(r1c.z); ev[13] = b2f_hi(r1c.z); ev[14] = b2f_lo(r1c.w); ev[15] = b2f_hi(r1c.w);
                float z[CPL];
#pragma unroll
                for (int j = 0; j < CPL; ++j) z[j] = pd[j] + psc[j];
#pragma unroll
                for (int k = 0; k < 16; ++k)
#pragma unroll
                    for (int j = 0; j < CPL; ++j) z[j] += ev[k] * w16[k][j];
#pragma unroll
                for (int j = 0; j < CPL; ++j) acc[j] += fmaxf(z[j], 0.f);
            }
        }
        const float invd = (deg > 0) ? 1.f / (float)deg : 0.f;
        float m[CPL];
#pragma unroll
        for (int j = 0; j < CPL; ++j) m[j] = acc[j] * invd;
        const int co = (sl < Fo) ? sl : 0;
        float yv = 0.f;
#pragma unroll
        for (int k = 0; k < H; ++k)
            yv += __shfl(m[k % CPL], sub * SL + k / CPL) * Wb_sh[k * Fo + co];
        if (sl < Fo)
            y[(size_t)v * Fo + sl] = (deg > 0) ? (yv + bb[sl]) : 0.f;
    }
}

// ---------------- BN stats + normalize ----------------
template <int Fo>
__global__ __launch_bounds__(256) void stats2_k(const float* __restrict__ y, float* __restrict__ stats) {
    __shared__ float sh[2 * Fo];
    for (int i = threadIdx.x; i < 2 * Fo; i += 256) sh[i] = 0.f;
    __syncthreads();
    const int co = threadIdx.x % Fo;
    float s1 = 0.f, s2 = 0.f;
    const long long total = (long long)N_NODES * Fo;
    for (long long i = (long long)blockIdx.x * 256 + threadIdx.x; i < total; i += (long long)gridDim.x * 256) {
        float v = y[i];
        s1 += v; s2 += v * v;
    }
    atomicAdd(&sh[co], s1);
    atomicAdd(&sh[Fo + co], s2);
    __syncthreads();
    if (threadIdx.x < 2 * Fo) atomicAdd(&stats[threadIdx.x], sh[threadIdx.x]);
}

template <int Fo>
__global__ __launch_bounds__(256) void bnrelu_k(float* __restrict__ y,
        const float* __restrict__ stats, const float* __restrict__ g, const float* __restrict__ beta) {
    int idx = blockIdx.x * 256 + threadIdx.x;
    if (idx >= N_NODES * Fo) return;
    int co = idx % Fo;
    const float invN = 1.0f / (float)N_NODES;
    float mu = stats[co] * invN;
    float ex2 = stats[Fo + co] * invN;
    float var = fmaxf(ex2 - mu * mu, 0.f);
    float rs = rsqrtf(var + 1e-5f);
    y[idx] = fmaxf((y[idx] - mu) * rs * g[co] + beta[co], 0.f);
}

// ---------------- pooling & head ----------------
__global__ __launch_bounds__(256) void pool_k(const float* __restrict__ h,
        const int* __restrict__ batch, float* __restrict__ pool, int* __restrict__ gcnt) {
    int idx = blockIdx.x * 256 + threadIdx.x;
    if (idx >= N_NODES * 16) return;
    int v = idx >> 4, c = idx & 15;
    int b = batch[v];
    atomicAdd(&pool[b * 16 + c], h[idx]);
    if (c == 0) atomicAdd(&gcnt[b], 1);
}

__global__ __launch_bounds__(256) void out_k(const float* __restrict__ pool,
        const int* __restrict__ gcnt, const float* __restrict__ Wfc,
        const float* __restrict__ bfc, float* __restrict__ out) {
    int idx = blockIdx.x * 256 + threadIdx.x;
    if (idx >= NUM_GRAPHS * 12) return;
    int g = idx / 12, o = idx % 12;
    int cnt = gcnt[g];
    float inv = 1.0f / (float)(cnt > 0 ? cnt : 1);
    float acc = bfc[o];
#pragma unroll
    for (int k = 0; k < 16; ++k) acc += pool[g * 16 + k] * inv * Wfc[k * 12 + o];
    out[idx] = 1.0f / (1.0f + expf(-acc));
}

template <typename ST>
static void run_pipeline(void* const* d_in, void* d_out, char* base, hipStream_t stream) {
    const size_t N = N_NODES, E = N_EDGES, G = NUM_GRAPHS;
    const float* x = (const float*)d_in[0];
    const float* ea = (const float*)d_in[1];
    const int* ei = (const int*)d_in[2];
    const int* srcv = ei;
    const int* dstv = ei + E;
    const int* batch = (const int*)d_in[3];
    const float* Wn = (const float*)d_in[5];  const float* bn_ = (const float*)d_in[6];
    const float* We = (const float*)d_in[7];  const float* be_ = (const float*)d_in[8];
    const float* W1a = (const float*)d_in[9]; const float* b1a = (const float*)d_in[10];
    const float* W1b = (const float*)d_in[11]; const float* b1b = (const float*)d_in[12];
    const float* W2a = (const float*)d_in[13]; const float* b2a = (const float*)d_in[14];
    const float* W2b = (const float*)d_in[15]; const float* b2b = (const float*)d_in[16];
    const float* W3a = (const float*)d_in[17]; const float* b3a = (const float*)d_in[18];
    const float* W3b = (const float*)d_in[19]; const float* b3b = (const float*)d_in[20];
    const float* g1 = (const float*)d_in[21]; const float* be1 = (const float*)d_in[22];
    const float* g2 = (const float*)d_in[23]; const float* be2 = (const float*)d_in[24];
    const float* g3 = (const float*)d_in[25]; const float* be3 = (const float*)d_in[26];
    const float* Wfc = (const float*)d_in[27]; const float* bfc = (const float*)d_in[28];

    size_t off = 0;
    auto take = [&](size_t bytes) { size_t o = off; off += (bytes + 255) & ~(size_t)255; return o; };
    int* hist = (int*)(base + take(N * 4));
    int* cursor = (int*)(base + take(N * 4));
    int* row_ptr = (int*)(base + take((N + 1) * 4));
    int* bsum = (int*)(base + take(256 * 4));
    int* boff = (int*)(base + take(256 * 4));
    int* sorted = (int*)(base + take(E * 4));
    int* srcs = (int*)(base + take(E * 4));
    float* hbuf = (float*)(base + take(N * 64 * 4));
    ST* Pd = (ST*)(base + take(N * 128 * sizeof(ST)));
    ST* Ps = (ST*)(base + take(N * 128 * sizeof(ST)));
    u16* e16s = (u16*)(base + take(E * 16 * 2));
    float* stats = (float*)(base + take(256 * 4));
    float* pool = (float*)(base + take(G * 16 * 4));
    int* gcnt = (int*)(base + take(G * 4));

    const int NB = (N_NODES + 1023) / 1024;

    // CSR build (+ srcs in sorted order)
    hipMemsetAsync(hist, 0, N * 4, stream);
    hist_k<<<dim3((E + 255) / 256), dim3(256), 0, stream>>>(dstv, hist);
    scan_part_k<<<dim3(NB), dim3(256), 0, stream>>>(hist, cursor, bsum);
    scan_top_k<<<dim3(1), dim3(256), 0, stream>>>(bsum, boff, NB, &row_ptr[N_NODES]);
    scan_add_k<<<dim3((N + 255) / 256), dim3(256), 0, stream>>>(cursor, boff, row_ptr, cursor);
    scatter_k<<<dim3((E + 255) / 256), dim3(256), 0, stream>>>(srcv, dstv, cursor, sorted, srcs);

    // embeddings (e16 in CSR order)
    edge_emb_k<<<dim3((E * 16 + 255) / 256), dim3(256), 0, stream>>>(ea, We, be_, sorted, e16s);
    node_emb_k<<<dim3((N * 64 + 255) / 256), dim3(256), 0, stream>>>(x, Wn, bn_, hbuf);

    // conv1: F=64, H=128, Fo=64
    proj_k<64, 128, ST><<<dim3((N * 128 + 255) / 256), dim3(256), 0, stream>>>(hbuf, W1a, b1a, Pd, Ps);
    conv_k<128, 64, ST><<<dim3(1280), dim3(256), 0, stream>>>(row_ptr, srcs, e16s, Pd, Ps,
            W1a + 128 * 128, W1b, b1b, hbuf);
    hipMemsetAsync(stats, 0, 256 * 4, stream);
    stats2_k<64><<<dim3(512), dim3(256), 0, stream>>>(hbuf, stats);
    bnrelu_k<64><<<dim3((N * 64 + 255) / 256), dim3(256), 0, stream>>>(hbuf, stats, g1, be1);

    // conv2: F=64, H=64, Fo=32
    proj_k<64, 64, ST><<<dim3((N * 64 + 255) / 256), dim3(256), 0, stream>>>(hbuf, W2a, b2a, Pd, Ps);
    conv_k<64, 32, ST><<<dim3(2048), dim3(256), 0, stream>>>(row_ptr, srcs, e16s, Pd, Ps,
            W2a + 128 * 64, W2b, b2b, hbuf);
    hipMemsetAsync(stats, 0, 256 * 4, stream);
    stats2_k<32><<<dim3(512), dim3(256), 0, stream>>>(hbuf, stats);
    bnrelu_k<32><<<dim3((N * 32 + 255) / 256), dim3(256), 0, stream>>>(hbuf, stats, g2, be2);

    // conv3: F=32, H=32, Fo=16 (2 nodes/wave)
    proj_k<32, 32, ST><<<dim3((N * 32 + 255) / 256), dim3(256), 0, stream>>>(hbuf, W3a, b3a, Pd, Ps);
    conv_k<32, 16, ST><<<dim3(2048), dim3(256), 0, stream>>>(row_ptr, srcs, e16s, Pd, Ps,
            W3a + 64 * 32, W3b, b3b, hbuf);
    hipMemsetAsync(stats, 0, 256 * 4, stream);
    stats2_k<16><<<dim3(512), dim3(256), 0, stream>>>(hbuf, stats);
    bnrelu_k<16><<<dim3((N * 16 + 255) / 256), dim3(256), 0, stream>>>(hbuf, stats, g3, be3);

    // pool + head
    hipMemsetAsync(pool, 0, G * 16 * 4, stream);
    hipMemsetAsync(gcnt, 0, G * 4, stream);
    pool_k<<<dim3((N * 16 + 255) / 256), dim3(256), 0, stream>>>(hbuf, batch, pool, gcnt);
    out_k<<<dim3((G * 12 + 255) / 256), dim3(256), 0, stream>>>(pool, gcnt, Wfc, bfc, (float*)d_out);
}

extern "C" void kernel_launch(void* const* d_in, const int* in_sizes, int n_in,
                              void* d_out, int out_size, void* d_ws, size_t ws_size,
                              hipStream_t stream) {
    const size_t N = N_NODES, E = N_EDGES, G = NUM_GRAPHS;
    auto need = [&](size_t stbytes) {
        size_t o = 0;
        auto take = [&](size_t b) { o += (b + 255) & ~(size_t)255; };
        take(N * 4); take(N * 4); take((N + 1) * 4); take(256 * 4); take(256 * 4);
        take(E * 4); take(E * 4); take(N * 64 * 4);
        take(N * 128 * stbytes); take(N * 128 * stbytes);
        take(E * 16 * 2);
        take(256 * 4); take(G * 16 * 4); take(G * 4);
        return o;
    };
    if (ws_size >= need(4)) {
        run_pipeline<float>(d_in, d_out, (char*)d_ws, stream);   // fp32 staging
    } else if (ws_size >= need(2)) {
        run_pipeline<u16>(d_in, d_out, (char*)d_ws, stream);     // bf16 staging fallback
    } else {
        fprintf(stderr, "kernel_launch: ws too small: need %zu have %zu\n", need(2), ws_size);
    }
}